// Round 14
// baseline (493.302 us; speedup 1.0000x reference)
//
#include <hip/hip_runtime.h>
#include <hip/hip_bf16.h>
#include <stdint.h>

#define N_TOK 4096
#define DIM   1024
#define NE    8
#define HID   4096
#define OUTD  1024
#define TOPK  2
#define SLOTS (N_TOK*TOPK)

typedef __bf16 bf16_t;
typedef __attribute__((ext_vector_type(8))) __bf16 bf16x8;
typedef __attribute__((ext_vector_type(4))) __bf16 bf16x4;
typedef __attribute__((ext_vector_type(4))) float  f32x4;

static __device__ __forceinline__ uint32_t pk2(float a, float b) {
    __bf16 x = (__bf16)a, y = (__bf16)b;
    return (uint32_t)__builtin_bit_cast(uint16_t, x) |
          ((uint32_t)__builtin_bit_cast(uint16_t, y) << 16);
}

// ---------------- gating (fp64 logits, top-2, softmax) + x -> bf16 cast ----------------
__global__ __launch_bounds__(512)
void k_prep(const float* __restrict__ x, const float* __restrict__ wg,
            bf16_t* __restrict__ xb,
            int* __restrict__ tki, float* __restrict__ tkg,
            int* __restrict__ counts, float* __restrict__ imp) {
    int n = blockIdx.x * 8 + (threadIdx.x >> 6);
    int lane = threadIdx.x & 63;
    const float* xr = x + (size_t)n * DIM;
    double acc[NE];
#pragma unroll
    for (int e = 0; e < NE; ++e) acc[e] = 0.0;
#pragma unroll
    for (int i = 0; i < 4; ++i) {
        int d0 = i * 256 + lane * 4;
        float4 v = *(const float4*)&xr[d0];
        bf16x4 o;
        o[0] = (__bf16)v.x; o[1] = (__bf16)v.y; o[2] = (__bf16)v.z; o[3] = (__bf16)v.w;
        *(bf16x4*)&xb[(size_t)n * DIM + d0] = o;
        const float* wr = wg + (size_t)d0 * NE;
#pragma unroll
        for (int j = 0; j < 4; ++j) {
            double xv = (double)((&v.x)[j]);
#pragma unroll
            for (int e = 0; e < NE; ++e) acc[e] += xv * (double)wr[j * NE + e];
        }
    }
#pragma unroll
    for (int e = 0; e < NE; ++e)
        for (int off = 32; off > 0; off >>= 1) acc[e] += __shfl_xor(acc[e], off);
    if (lane == 0) {
        int i0 = 0; double v0 = acc[0];
#pragma unroll
        for (int e = 1; e < NE; ++e) if (acc[e] > v0) { v0 = acc[e]; i0 = e; }
        int i1 = -1; double v1 = -1e300;
#pragma unroll
        for (int e = 0; e < NE; ++e) if (e != i0 && acc[e] > v1) { v1 = acc[e]; i1 = e; }
        double e1 = exp(v1 - v0);
        double s = 1.0 + e1;
        float g0 = (float)(1.0 / s), g1 = (float)(e1 / s);
        tki[n*2]   = i0;  tki[n*2+1] = i1;
        tkg[n*2]   = g0;  tkg[n*2+1] = g1;
        atomicAdd(&counts[i0], 1);
        atomicAdd(&counts[i1], 1);
        atomicAdd(&imp[i0], g0);
        atomicAdd(&imp[i1], g1);
    }
}

// ---------------- aux loss + prefix-sum bases ----------------
__global__ void k_finalize(const float* __restrict__ imp, const int* __restrict__ counts,
                           int* __restrict__ bases, float* __restrict__ aux_out) {
    if (threadIdx.x == 0 && blockIdx.x == 0) {
        float m = 0.f;
        for (int e = 0; e < NE; ++e) m += imp[e];
        m /= (float)NE;
        float var = 0.f;
        for (int e = 0; e < NE; ++e) { float d = imp[e] - m; var += d * d; }
        var /= (float)NE;
        aux_out[0] = 0.01f * var / (m * m + 1e-10f);
        int b = 0;
        for (int e = 0; e < NE; ++e) { bases[e] = b; b += counts[e]; }
    }
}

// ---------------- build per-expert token lists + inverse slot map ----------------
__global__ void k_build(const int* __restrict__ tki,
                        const int* __restrict__ bases, int* __restrict__ cursor,
                        int* __restrict__ tok_ids, int* __restrict__ slotmap) {
    int i = blockIdx.x * 256 + threadIdx.x;
    if (i < SLOTS) {
        int e = tki[i];
        int p = atomicAdd(&cursor[e], 1);
        int s = bases[e] + p;
        tok_ids[s] = i >> 1;
        slotmap[i] = s;
    }
}

// ====== grouped GEMM, 256x256 tile, BK=32, 8 waves (2M x 4N), per-wave 128x64 ======
// FUSED WEIGHT TRANSPOSE: B read directly from native fp32 weights (K-outer layout).
// Per K-tile, each thread loads rows {2kq,2kq+1} cols nb8..+7 (4 x float4, rows 1KB
// contiguous -> coalesced), cvt fp32->bf16, and writes 8 packed k-pair ds_write_b32 into
// LDS laid out [n][k] with swizzle k' = k ^ ((((n>>1)^(n>>4))&3)<<3) (write banks 2-way
// same-dword = free; read conflict structure identical to prior proven-0-conflict layout
// since r>>4 is constant per read instr). A-side global_load_lds staging unchanged.
// Pipeline (3 bufs, 1 barrier/iter): reads(T)+MFMA(T) ; vmcnt(0) [stage T+1 landed,
// issued one iter ago -> hidden under reads+MFMA] ; cvt+dswrite B(T+1) ; issue stage(T+2)
// (2 A-GLL + 4 B-loads) ; lgkm(0) ; barrier [publish T+1]. Buffer (T+2)%3 was last read
// at iter T-1 (reads lgkm-retired pre-MFMA, 2 barriers ago) -> race-free.
// MODE 0: hbuf[slot] = relu(x_gather @ W1 + b1)   (B = w1 [D][H] fp32)
// MODE 1 (KSPLIT=2): ybuf[kslot][slot] = h @ W2 (+b2 on kslot 0)   (B = w2 [H][O] fp32)
template <int MODE>
__global__ __launch_bounds__(512, 2)
void k_gemm(const bf16_t* __restrict__ A,    // MODE0: xb [N][DIM]; MODE1: hbuf [SLOTS][HID]
            const float* __restrict__ Bw,    // MODE0: w1 [E][DIM][HID]; MODE1: w2 [E][HID][OUTD]
            const float* __restrict__ bias,
            const int* __restrict__ tok_ids,
            const int* __restrict__ bases,
            const int* __restrict__ counts,
            bf16_t* __restrict__ Y) {
    constexpr int KD   = (MODE == 0) ? DIM : HID;    // A row stride, B row count
    constexpr int ND   = (MODE == 0) ? HID : OUTD;   // B col count
    constexpr int KLEN = (MODE == 0) ? DIM : (HID / 2);
    constexpr int KT   = KLEN / 32;                  // 32 / 64
    constexpr int BUFE = 16384;                      // A 8192 + B 8192 elems (32 KiB)

    const int e  = blockIdx.x & 7;            // expert pinned to XCD
    const int lb = blockIdx.x >> 3;           // 0..31
    const int ne = counts[e];
    if (ne == 0) return;
    const int b0 = bases[e];
    const int NTy = (ne + 255) >> 8;
    const int NTILES = (MODE == 0) ? (16 * NTy) : (8 * NTy);

    extern __shared__ bf16_t lds[];           // 3 * BUFE elems = 96 KiB

    const int t = threadIdx.x, w = t >> 6, L = t & 63;
    const int wm = w >> 2, wn = w & 3;        // 2M x 4N; per-wave out 128x64
    const int lr = L & 15, lq = L >> 4;
    const int srow  = L >> 2;                 // A staging: row within 16-row GLL group
    const int sslot = L & 3;                  // A staging: 16B chunk

    // B staging thread mapping: k-pair kq = t&15 (k = 2kq,2kq+1), n-chunk nb8 = (t>>4)*8
    const int kq  = t & 15;
    const int nb8 = (t >> 4) * 8;

    // fragment read offsets
    int offA[8], offB[4];
#pragma unroll
    for (int i = 0; i < 8; ++i) {
        int r = wm * 128 + i * 16 + lr;
        offA[i] = r * 32 + ((lq ^ ((r >> 1) & 3)) << 3);              // A: old swizzle
    }
#pragma unroll
    for (int j = 0; j < 4; ++j) {
        int r = wn * 64 + j * 16 + lr;
        offB[j] = 8192 + r * 32 + ((lq ^ (((r >> 1) ^ (r >> 4)) & 3)) << 3);  // B: new swizzle
    }
    // B LDS write element offsets (dword-aligned: elem is even)
    int wofs[8];
#pragma unroll
    for (int j = 0; j < 8; ++j) {
        int n = nb8 + j;
        int swz = ((n >> 1) ^ (n >> 4)) & 3;
        wofs[j] = 8192 + n * 32 + ((2 * kq) ^ (swz << 3));
    }
    // A stage LDS bases (wave-uniform)
    const int sdstA0 = (0 * 128 + w * 16) * 32;
    const int sdstA1 = (1 * 128 + w * 16) * 32;

#define GLL(srcp, dste) __builtin_amdgcn_global_load_lds( \
        (const __attribute__((address_space(1))) uint32_t*)(srcp), \
        (__attribute__((address_space(3))) uint32_t*)(lds + (dste)), 16, 0, 0)
#define AGLL(Tt, bsl) { \
        GLL(aptr[0] + (size_t)(Tt) * 32, (bsl) * BUFE + sdstA0); \
        GLL(aptr[1] + (size_t)(Tt) * 32, (bsl) * BUFE + sdstA1); }
#define BLOAD(Tt) { const float* bp_ = bs + (size_t)(Tt) * 32 * ND; \
        rb0 = *(const f32x4*)(bp_);      rb1 = *(const f32x4*)(bp_ + 4); \
        rb2 = *(const f32x4*)(bp_ + ND); rb3 = *(const f32x4*)(bp_ + ND + 4); }
#define BWRITE(dbase) { \
        _Pragma("unroll") for (int j_ = 0; j_ < 4; ++j_) { \
            *(uint32_t*)&lds[(dbase) + wofs[j_]]     = pk2(rb0[j_], rb2[j_]); \
            *(uint32_t*)&lds[(dbase) + wofs[4 + j_]] = pk2(rb1[j_], rb3[j_]); } }

    for (int ti = lb; ti < NTILES; ti += 32) {
        int panel = ti / NTy, y = ti - panel * NTy, kslot = 0;
        if (MODE == 1) { kslot = panel & 1; panel >>= 1; }
        const int m0 = y * 256, n0 = panel * 256;
        const int koff = (MODE == 0) ? 0 : kslot * KLEN;
        bf16_t* __restrict__ Yw = (MODE == 0) ? Y : (Y + (size_t)kslot * SLOTS * OUTD);

        // A stage pointers (bf16, pre-swizzled source col)
        const bf16_t* aptr[2];
#pragma unroll
        for (int g = 0; g < 2; ++g) {
            int row = g * 128 + w * 16 + srow;
            int gk  = sslot ^ ((row >> 1) & 3);
            int mm = m0 + row;
            int rr = (mm < ne) ? mm : (ne - 1);
            size_t arow = (MODE == 0) ? (size_t)tok_ids[b0 + rr] * KD : (size_t)(b0 + rr) * KD;
            aptr[g] = A + arow + koff + gk * 8;
        }
        // B source: rows (koff + T*32 + 2kq{,+1}), cols n0 + nb8..+7
        const float* bs = Bw + (size_t)e * KD * ND + (size_t)(koff + 2 * kq) * ND + n0 + nb8;

        f32x4 acc[8][4];
#pragma unroll
        for (int i = 0; i < 8; ++i)
#pragma unroll
            for (int j = 0; j < 4; ++j) acc[i][j] = (f32x4){0.f, 0.f, 0.f, 0.f};

        f32x4 rb0, rb1, rb2, rb3;

        // cover previous tile's last-iteration LDS reads before overwriting buffers
        __builtin_amdgcn_s_barrier();

        // prologue: tile 0 -> buf0 (A via GLL, B via reg+cvt+dswrite); issue stage(1)
        AGLL(0, 0);
        BLOAD(0);
        asm volatile("s_waitcnt vmcnt(0)" ::: "memory");
        BWRITE(0 * BUFE);
        AGLL(1, 1);
        BLOAD(1);
        asm volatile("s_waitcnt lgkmcnt(0)" ::: "memory");
        __builtin_amdgcn_s_barrier();     // tile 0 published

        int cb = 0;
        for (int T = 0; T < KT; ++T) {
            bf16x8 fb[4], fa[8];
#pragma unroll
            for (int j = 0; j < 4; ++j) fb[j] = *(const bf16x8*)(lds + cb * BUFE + offB[j]);
#pragma unroll
            for (int i = 0; i < 4; ++i) fa[i] = *(const bf16x8*)(lds + cb * BUFE + offA[i]);
            __builtin_amdgcn_sched_barrier(0);
#pragma unroll
            for (int i = 4; i < 8; ++i) fa[i] = *(const bf16x8*)(lds + cb * BUFE + offA[i]);
            __builtin_amdgcn_sched_barrier(0);
            asm volatile("s_waitcnt lgkmcnt(4)" ::: "memory");   // fb + fa0-3 done
            __builtin_amdgcn_sched_barrier(0);
            __builtin_amdgcn_s_setprio(1);
#pragma unroll
            for (int i = 0; i < 4; ++i)
#pragma unroll
                for (int j = 0; j < 4; ++j)
                    acc[i][j] = __builtin_amdgcn_mfma_f32_16x16x32_bf16(fb[j], fa[i], acc[i][j], 0, 0, 0);
            __builtin_amdgcn_s_setprio(0);
            asm volatile("s_waitcnt lgkmcnt(0)" ::: "memory");   // fa4-7 done (hidden under mh0)
            __builtin_amdgcn_sched_barrier(0);
            __builtin_amdgcn_s_setprio(1);
#pragma unroll
            for (int i = 4; i < 8; ++i)
#pragma unroll
                for (int j = 0; j < 4; ++j)
                    acc[i][j] = __builtin_amdgcn_mfma_f32_16x16x32_bf16(fb[j], fa[i], acc[i][j], 0, 0, 0);
            __builtin_amdgcn_s_setprio(0);

            if (T + 1 < KT) {
                const int nb = (T + 1 == 1) ? 1 : ((cb + 1) % 3);   // (T+1)%3
                asm volatile("s_waitcnt vmcnt(0)" ::: "memory");    // stage(T+1) landed
                BWRITE(nb * BUFE);
                if (T + 2 < KT) {
                    const int nb2 = (cb + 2) % 3;                    // (T+2)%3
                    AGLL(T + 2, nb2);
                    BLOAD(T + 2);
                }
                asm volatile("s_waitcnt lgkmcnt(0)" ::: "memory");   // my dswrites done
                __builtin_amdgcn_s_barrier();                        // publish tile T+1
            }
            cb = (cb == 2) ? 0 : cb + 1;
        }

        // ---------------- epilogue: bf16 store ----------------
        const int kbias = (MODE == 0) ? 1 : (kslot == 0 ? 1 : 0);
#pragma unroll
        for (int i = 0; i < 8; ++i) {
            int gm = m0 + wm * 128 + i * 16 + lr;
            if (gm < ne) {
#pragma unroll
                for (int j = 0; j < 4; ++j) {
                    int gn = n0 + wn * 64 + j * 16 + lq * 4;
                    f32x4 bv = *(const f32x4*)&bias[(size_t)e * ND + gn];
                    bf16x4 hv;
#pragma unroll
                    for (int r = 0; r < 4; ++r) {
                        float v = acc[i][j][r];
                        if (kbias) v += bv[r];
                        if (MODE == 0) v = fmaxf(v, 0.f);
                        hv[r] = (__bf16)v;
                    }
                    *(bf16x4*)&Yw[(size_t)(b0 + gm) * ND + gn] = hv;
                }
            }
        }
    }
#undef BWRITE
#undef BLOAD
#undef AGLL
#undef GLL
}

// ---------------- combine: out[n] = g0*(y0a+y0b) + g1*(y1a+y1b) (fp32) ----------------
__global__ void k_combine(const bf16_t* __restrict__ ybuf,   // [2][SLOTS][OUTD]
                          const int* __restrict__ slotmap,
                          const float* __restrict__ tkg,
                          float* __restrict__ out) {
    int n = blockIdx.x;
    int d = threadIdx.x * 4;
    int s0 = slotmap[2 * n], s1 = slotmap[2 * n + 1];
    float g0 = tkg[2 * n],  g1 = tkg[2 * n + 1];
    const bf16_t* y2 = ybuf + (size_t)SLOTS * OUTD;
    bf16x4 a0 = *(const bf16x4*)&ybuf[(size_t)s0 * OUTD + d];
    bf16x4 a1 = *(const bf16x4*)&y2  [(size_t)s0 * OUTD + d];
    bf16x4 c0 = *(const bf16x4*)&ybuf[(size_t)s1 * OUTD + d];
    bf16x4 c1 = *(const bf16x4*)&y2  [(size_t)s1 * OUTD + d];
    f32x4 o;
#pragma unroll
    for (int r = 0; r < 4; ++r)
        o[r] = g0 * ((float)a0[r] + (float)a1[r]) + g1 * ((float)c0[r] + (float)c1[r]);
    *(f32x4*)&out[(size_t)n * OUTD + d] = o;
}

extern "C" void kernel_launch(void* const* d_in, const int* in_sizes, int n_in,
                              void* d_out, int out_size, void* d_ws, size_t ws_size,
                              hipStream_t stream) {
    const float* x  = (const float*)d_in[0];
    const float* wg = (const float*)d_in[1];
    const float* w1 = (const float*)d_in[2];
    const float* b1 = (const float*)d_in[3];
    const float* w2 = (const float*)d_in[4];
    const float* b2 = (const float*)d_in[5];
    float* out = (float*)d_out;

    char* ws = (char*)d_ws;
    size_t o = 0;
    auto alloc = [&](size_t b) { size_t r = o; o = (o + b + 255) & ~(size_t)255; return r; };
    int*    counts  = (int*)(ws + alloc(NE * 4));
    int*    cursor  = (int*)(ws + alloc(NE * 4));
    int*    bases   = (int*)(ws + alloc(NE * 4));
    float*  imp     = (float*)(ws + alloc(NE * 4));
    int*    tki     = (int*)(ws + alloc(SLOTS * 4));
    float*  tkg     = (float*)(ws + alloc(SLOTS * 4));
    int*    tok_ids = (int*)(ws + alloc(SLOTS * 4));
    int*    slotmap = (int*)(ws + alloc(SLOTS * 4));
    bf16_t* xb      = (bf16_t*)(ws + alloc((size_t)N_TOK * DIM * 2));
    bf16_t* hbuf    = (bf16_t*)(ws + alloc((size_t)SLOTS * HID * 2));
    bf16_t* ybuf    = (bf16_t*)(ws + alloc((size_t)2 * SLOTS * OUTD * 2));
    (void)ws_size; (void)n_in; (void)in_sizes;

    hipFuncSetAttribute((const void*)&k_gemm<0>, hipFuncAttributeMaxDynamicSharedMemorySize, 98304);
    hipFuncSetAttribute((const void*)&k_gemm<1>, hipFuncAttributeMaxDynamicSharedMemorySize, 98304);

    hipMemsetAsync(ws, 0, 1024, stream);   // counts + cursor + bases + imp

    k_prep<<<N_TOK / 8, 512, 0, stream>>>(x, wg, xb, tki, tkg, counts, imp);
    k_finalize<<<1, 64, 0, stream>>>(imp, counts, bases, out + (size_t)N_TOK * OUTD);
    k_build<<<SLOTS / 256, 256, 0, stream>>>(tki, bases, cursor, tok_ids, slotmap);

    // 256 blocks = 8 XCD-pinned experts x 32 worklist slots; 96 KiB dynamic LDS
    k_gemm<0><<<256, 512, 98304, stream>>>(xb, w1, b1, tok_ids, bases, counts, hbuf);
    k_gemm<1><<<256, 512, 98304, stream>>>(hbuf, w2, b2, tok_ids, bases, counts, ybuf);

    k_combine<<<N_TOK, 256, 0, stream>>>(ybuf, slotmap, tkg, out);
}

// Round 15
// 358.308 us; speedup vs baseline: 1.3768x; 1.3768x over previous
//
#include <hip/hip_runtime.h>
#include <hip/hip_bf16.h>
#include <stdint.h>

#define N_TOK 4096
#define DIM   1024
#define NE    8
#define HID   4096
#define OUTD  1024
#define TOPK  2
#define SLOTS (N_TOK*TOPK)

typedef __bf16 bf16_t;
typedef __attribute__((ext_vector_type(8))) __bf16 bf16x8;
typedef __attribute__((ext_vector_type(4))) __bf16 bf16x4;
typedef __attribute__((ext_vector_type(4))) float  f32x4;

static __device__ __forceinline__ uint32_t pk2(float a, float b) {
    __bf16 x = (__bf16)a, y = (__bf16)b;
    return (uint32_t)__builtin_bit_cast(uint16_t, x) |
          ((uint32_t)__builtin_bit_cast(uint16_t, y) << 16);
}

// ---------------- gating (fp64 logits, top-2, softmax) + x -> bf16 cast ----------------
// NO atomics (R15): counts/imp computed by k_count, placement by k_place.
__global__ __launch_bounds__(512)
void k_gating(const float* __restrict__ x, const float* __restrict__ wg,
              bf16_t* __restrict__ xb,
              int* __restrict__ tki, float* __restrict__ tkg) {
    int n = blockIdx.x * 8 + (threadIdx.x >> 6);
    int lane = threadIdx.x & 63;
    const float* xr = x + (size_t)n * DIM;
    double acc[NE];
#pragma unroll
    for (int e = 0; e < NE; ++e) acc[e] = 0.0;
#pragma unroll
    for (int i = 0; i < 4; ++i) {
        int d0 = i * 256 + lane * 4;
        float4 v = *(const float4*)&xr[d0];
        bf16x4 o;
        o[0] = (__bf16)v.x; o[1] = (__bf16)v.y; o[2] = (__bf16)v.z; o[3] = (__bf16)v.w;
        *(bf16x4*)&xb[(size_t)n * DIM + d0] = o;
        const float* wr = wg + (size_t)d0 * NE;
#pragma unroll
        for (int j = 0; j < 4; ++j) {
            double xv = (double)((&v.x)[j]);
#pragma unroll
            for (int e = 0; e < NE; ++e) acc[e] += xv * (double)wr[j * NE + e];
        }
    }
#pragma unroll
    for (int e = 0; e < NE; ++e)
        for (int off = 32; off > 0; off >>= 1) acc[e] += __shfl_xor(acc[e], off);
    if (lane == 0) {
        int i0 = 0; double v0 = acc[0];
#pragma unroll
        for (int e = 1; e < NE; ++e) if (acc[e] > v0) { v0 = acc[e]; i0 = e; }
        int i1 = -1; double v1 = -1e300;
#pragma unroll
        for (int e = 0; e < NE; ++e) if (e != i0 && acc[e] > v1) { v1 = acc[e]; i1 = e; }
        double e1 = exp(v1 - v0);
        double s = 1.0 + e1;
        tki[n*2]   = i0;  tki[n*2+1] = i1;
        tkg[n*2]   = (float)(1.0 / s);
        tkg[n*2+1] = (float)(e1 / s);
    }
}

// ---------------- per-expert count + importance (deterministic tree, no atomics) ----------------
__global__ void k_count(const int* __restrict__ tki, const float* __restrict__ tkg,
                        int* __restrict__ counts, float* __restrict__ imp) {
    int e = blockIdx.x, t = threadIdx.x;
    __shared__ int   rc[256];
    __shared__ float rg[256];
    int c = 0; float g = 0.f;
    for (int i = t; i < SLOTS; i += 256)
        if (tki[i] == e) { ++c; g += tkg[i]; }
    rc[t] = c; rg[t] = g; __syncthreads();
    for (int off = 128; off > 0; off >>= 1) {
        if (t < off) { rc[t] += rc[t + off]; rg[t] += rg[t + off]; }
        __syncthreads();
    }
    if (t == 0) { counts[e] = rc[0]; imp[e] = rg[0]; }
}

// ---------------- aux loss + prefix-sum bases ----------------
__global__ void k_finalize(const float* __restrict__ imp, const int* __restrict__ counts,
                           int* __restrict__ bases, float* __restrict__ aux_out) {
    if (threadIdx.x == 0 && blockIdx.x == 0) {
        float m = 0.f;
        for (int e = 0; e < NE; ++e) m += imp[e];
        m /= (float)NE;
        float var = 0.f;
        for (int e = 0; e < NE; ++e) { float d = imp[e] - m; var += d * d; }
        var /= (float)NE;
        aux_out[0] = 0.01f * var / (m * m + 1e-10f);
        int b = 0;
        for (int e = 0; e < NE; ++e) { bases[e] = b; b += counts[e]; }
    }
}

// ---------------- placement: ballot prefix-scan per expert (deterministic, no atomics) ----------------
__global__ __launch_bounds__(256)
void k_place(const int* __restrict__ tki, const int* __restrict__ bases,
             int* __restrict__ tok_ids, int* __restrict__ slotmap) {
    int e = blockIdx.x, t = threadIdx.x;
    int wid = t >> 6, lane = t & 63;
    __shared__ int wc[4];
    int run = bases[e];
    for (int base = 0; base < SLOTS; base += 256) {
        int i = base + t;
        bool f = (tki[i] == e);
        unsigned long long b = __ballot(f);
        int pre = __popcll(b & ((1ull << lane) - 1ull));
        if (lane == 0) wc[wid] = __popcll(b);
        __syncthreads();
        int woff = 0;
#pragma unroll
        for (int u = 0; u < 4; ++u) if (u < wid) woff += wc[u];
        int tot = wc[0] + wc[1] + wc[2] + wc[3];
        if (f) { int s = run + woff + pre; tok_ids[s] = i >> 1; slotmap[i] = s; }
        run += tot;
        __syncthreads();
    }
}

// ---------------- W [E][R][C] fp32 -> Wt [E][C][R] bf16 ----------------
// R15 v3 geometry: 256(src rows) x 64(src cols) tiles, 512 thr. LDS holds the tile
// ALREADY transposed (tT[col][row], pair-packed b32 writes), rows padded to 264 elems
// (528B = 33x16B: b128-aligned reads). Global writes: 32 lanes x 16B = 512B contiguous
// per out-row, 2 rows/instr. Reads: 256B x 4 segments/instr (4 rows).
__global__ __launch_bounds__(512)
void k_transpose(const float* __restrict__ w1, const float* __restrict__ w2,
                 bf16_t* __restrict__ w1t, bf16_t* __restrict__ w2t) {
    __shared__ bf16_t tT[64][264];        // 33.8 KB
    const int bx = blockIdx.x;
    const float* src; bf16_t* dst; int R, C, ry, cx;
    if (bx < 2048) {                      // w1: [8][1024][4096] -> [8][4096][1024]
        int e = bx >> 8, rem = bx & 255;  // 4 ry x 64 cx
        ry = rem >> 6; cx = rem & 63;
        src = w1 + (size_t)e * DIM * HID; dst = w1t + (size_t)e * DIM * HID;
        R = DIM; C = HID;
    } else {                              // w2: [8][4096][1024] -> [8][1024][4096]
        int b2 = bx - 2048;
        int e = b2 >> 8, rem = b2 & 255;  // 16 ry x 16 cx
        ry = rem >> 4; cx = rem & 15;
        src = w2 + (size_t)e * HID * OUTD; dst = w2t + (size_t)e * HID * OUTD;
        R = HID; C = OUTD;
    }
    const int r0 = ry * 256, c0 = cx * 64;
    const int tx = threadIdx.x & 15;      // col quad
    const int ta = threadIdx.x >> 4;      // row-pair 0..31
#pragma unroll
    for (int p = 0; p < 4; ++p) {
        int r = 2 * ta + 64 * p;
        float4 va = *(const float4*)&src[(size_t)(r0 + r)     * C + c0 + tx * 4];
        float4 vb = *(const float4*)&src[(size_t)(r0 + r + 1) * C + c0 + tx * 4];
#pragma unroll
        for (int j = 0; j < 4; ++j)
            *(uint32_t*)&tT[tx * 4 + j][r] = pk2((&va.x)[j], (&vb.x)[j]);
    }
    __syncthreads();
    const int w = threadIdx.x >> 6, l = threadIdx.x & 63;
    const int ccb = w * 2 + (l >> 5);     // 0..15
    const int rb  = (l & 31) * 8;
#pragma unroll
    for (int q = 0; q < 4; ++q) {
        int cc = q * 16 + ccb;
        bf16x8 o = *(const bf16x8*)&tT[cc][rb];
        *(bf16x8*)&dst[(size_t)(c0 + cc) * R + r0 + rb] = o;
    }
}

// ====== grouped GEMM, 256x256 tile, BK=32, 8 waves (2M x 4N), per-wave 128x64 ======
// (verbatim R13 — passing, ~100 us each)
template <int MODE>
__global__ __launch_bounds__(512, 2)
void k_gemm(const bf16_t* __restrict__ A,    // MODE0: xb [N][DIM]; MODE1: hbuf [SLOTS][HID]
            const bf16_t* __restrict__ Bt,   // MODE0: w1t [E][HID][DIM]; MODE1: w2t [E][OUTD][HID]
            const float* __restrict__ bias,
            const int* __restrict__ tok_ids,
            const int* __restrict__ bases,
            const int* __restrict__ counts,
            bf16_t* __restrict__ Y) {
    constexpr int KD   = (MODE == 0) ? DIM : HID;
    constexpr int ND   = (MODE == 0) ? HID : OUTD;
    constexpr int KLEN = (MODE == 0) ? DIM : (HID / 2);   // 1024 / 2048
    constexpr int KT   = KLEN / 32;                       // 32 / 64
    constexpr int BUFE = 16384;               // A 8192 + B 8192 elems (32 KiB)

    const int e  = blockIdx.x & 7;            // expert pinned to XCD
    const int lb = blockIdx.x >> 3;           // 0..31
    const int ne = counts[e];
    if (ne == 0) return;
    const int b0 = bases[e];
    const int NTy = (ne + 255) >> 8;
    const int NTILES = (MODE == 0) ? (16 * NTy) : (8 * NTy);

    extern __shared__ bf16_t lds[];           // 3 * BUFE elems = 96 KiB

    const int t = threadIdx.x, w = t >> 6, L = t & 63;
    const int wm = w >> 2, wn = w & 3;        // 2M x 4N; per-wave out 128x64
    const int lr = L & 15, lq = L >> 4;
    const int srow  = L >> 2;
    const int sslot = L & 3;

    int offA[8], offB[4];
#pragma unroll
    for (int i = 0; i < 8; ++i) {
        int r = wm * 128 + i * 16 + lr;
        offA[i] = r * 32 + ((lq ^ ((r >> 1) & 3)) << 3);
    }
#pragma unroll
    for (int j = 0; j < 4; ++j) {
        int r = wn * 64 + j * 16 + lr;
        offB[j] = 8192 + r * 32 + ((lq ^ ((r >> 1) & 3)) << 3);
    }
    int sdstA[2], sdstB[2];
#pragma unroll
    for (int g = 0; g < 2; ++g) {
        sdstA[g] = (g * 128 + w * 16) * 32;
        sdstB[g] = 8192 + (g * 128 + w * 16) * 32;
    }

#define GLL(srcp, dste) __builtin_amdgcn_global_load_lds( \
        (const __attribute__((address_space(1))) uint32_t*)(srcp), \
        (__attribute__((address_space(3))) uint32_t*)(lds + (dste)), 16, 0, 0)
#define STAGE(Tt, bsl) { \
        _Pragma("unroll") for (int g_ = 0; g_ < 2; ++g_) { \
            GLL(aptr[g_] + (Tt) * 32, (bsl) * BUFE + sdstA[g_]); \
            GLL(bptr[g_] + (Tt) * 32, (bsl) * BUFE + sdstB[g_]); } }

    for (int ti = lb; ti < NTILES; ti += 32) {
        int panel = ti / NTy, y = ti - panel * NTy, kslot = 0;
        if (MODE == 1) { kslot = panel & 1; panel >>= 1; }
        const int m0 = y * 256, n0 = panel * 256;
        const int koff = (MODE == 0) ? 0 : kslot * KLEN;
        bf16_t* __restrict__ Yw = (MODE == 0) ? Y : (Y + (size_t)kslot * SLOTS * OUTD);

        const bf16_t* aptr[2];
        const bf16_t* bptr[2];
#pragma unroll
        for (int g = 0; g < 2; ++g) {
            int row = g * 128 + w * 16 + srow;
            int gk  = sslot ^ ((row >> 1) & 3);
            int mm = m0 + row;
            int rr = (mm < ne) ? mm : (ne - 1);
            size_t arow = (MODE == 0) ? (size_t)tok_ids[b0 + rr] * KD : (size_t)(b0 + rr) * KD;
            aptr[g] = A + arow + koff + gk * 8;
            bptr[g] = Bt + ((size_t)e * ND + n0 + row) * KD + koff + gk * 8;
        }

        f32x4 acc[8][4];
#pragma unroll
        for (int i = 0; i < 8; ++i)
#pragma unroll
            for (int j = 0; j < 4; ++j) acc[i][j] = (f32x4){0.f, 0.f, 0.f, 0.f};

        // cover previous tile's last-iteration LDS reads before overwriting buf0/buf1
        __builtin_amdgcn_s_barrier();

        STAGE(0, 0); STAGE(1, 1);

        int cb = 0;
        int nb = 2;
        for (int T = 0; T < KT; ++T) {
            if (T < KT - 1) { asm volatile("s_waitcnt vmcnt(4)" ::: "memory"); }
            else            { asm volatile("s_waitcnt vmcnt(0)" ::: "memory"); }
            __builtin_amdgcn_s_barrier();
            if (T + 2 < KT) STAGE(T + 2, nb);

            bf16x8 fb[4], fa[8];
#pragma unroll
            for (int j = 0; j < 4; ++j) fb[j] = *(const bf16x8*)(lds + cb * BUFE + offB[j]);
#pragma unroll
            for (int i = 0; i < 4; ++i) fa[i] = *(const bf16x8*)(lds + cb * BUFE + offA[i]);
            __builtin_amdgcn_sched_barrier(0);
#pragma unroll
            for (int i = 4; i < 8; ++i) fa[i] = *(const bf16x8*)(lds + cb * BUFE + offA[i]);
            __builtin_amdgcn_sched_barrier(0);
            asm volatile("s_waitcnt lgkmcnt(4)" ::: "memory");   // fb + fa0-3 done
            __builtin_amdgcn_sched_barrier(0);
            __builtin_amdgcn_s_setprio(1);
#pragma unroll
            for (int i = 0; i < 4; ++i)
#pragma unroll
                for (int j = 0; j < 4; ++j)
                    acc[i][j] = __builtin_amdgcn_mfma_f32_16x16x32_bf16(fb[j], fa[i], acc[i][j], 0, 0, 0);
            __builtin_amdgcn_s_setprio(0);
            asm volatile("s_waitcnt lgkmcnt(0)" ::: "memory");   // fa4-7 done (hidden under mh0)
            __builtin_amdgcn_sched_barrier(0);
            __builtin_amdgcn_s_setprio(1);
#pragma unroll
            for (int i = 4; i < 8; ++i)
#pragma unroll
                for (int j = 0; j < 4; ++j)
                    acc[i][j] = __builtin_amdgcn_mfma_f32_16x16x32_bf16(fb[j], fa[i], acc[i][j], 0, 0, 0);
            __builtin_amdgcn_s_setprio(0);

            cb = (cb == 2) ? 0 : cb + 1;
            nb = (nb == 2) ? 0 : nb + 1;
        }

        const int kbias = (MODE == 0) ? 1 : (kslot == 0 ? 1 : 0);
#pragma unroll
        for (int i = 0; i < 8; ++i) {
            int gm = m0 + wm * 128 + i * 16 + lr;
            if (gm < ne) {
#pragma unroll
                for (int j = 0; j < 4; ++j) {
                    int gn = n0 + wn * 64 + j * 16 + lq * 4;
                    f32x4 bv = *(const f32x4*)&bias[(size_t)e * ND + gn];
                    bf16x4 hv;
#pragma unroll
                    for (int r = 0; r < 4; ++r) {
                        float v = acc[i][j][r];
                        if (kbias) v += bv[r];
                        if (MODE == 0) v = fmaxf(v, 0.f);
                        hv[r] = (__bf16)v;
                    }
                    *(bf16x4*)&Yw[(size_t)(b0 + gm) * ND + gn] = hv;
                }
            }
        }
    }
#undef STAGE
#undef GLL
}

// ---------------- combine: out[n] = g0*(y0a+y0b) + g1*(y1a+y1b) (fp32) ----------------
__global__ void k_combine(const bf16_t* __restrict__ ybuf,   // [2][SLOTS][OUTD]
                          const int* __restrict__ slotmap,
                          const float* __restrict__ tkg,
                          float* __restrict__ out) {
    int n = blockIdx.x;
    int d = threadIdx.x * 4;
    int s0 = slotmap[2 * n], s1 = slotmap[2 * n + 1];
    float g0 = tkg[2 * n],  g1 = tkg[2 * n + 1];
    const bf16_t* y2 = ybuf + (size_t)SLOTS * OUTD;
    bf16x4 a0 = *(const bf16x4*)&ybuf[(size_t)s0 * OUTD + d];
    bf16x4 a1 = *(const bf16x4*)&y2  [(size_t)s0 * OUTD + d];
    bf16x4 c0 = *(const bf16x4*)&ybuf[(size_t)s1 * OUTD + d];
    bf16x4 c1 = *(const bf16x4*)&y2  [(size_t)s1 * OUTD + d];
    f32x4 o;
#pragma unroll
    for (int r = 0; r < 4; ++r)
        o[r] = g0 * ((float)a0[r] + (float)a1[r]) + g1 * ((float)c0[r] + (float)c1[r]);
    *(f32x4*)&out[(size_t)n * OUTD + d] = o;
}

extern "C" void kernel_launch(void* const* d_in, const int* in_sizes, int n_in,
                              void* d_out, int out_size, void* d_ws, size_t ws_size,
                              hipStream_t stream) {
    const float* x  = (const float*)d_in[0];
    const float* wg = (const float*)d_in[1];
    const float* w1 = (const float*)d_in[2];
    const float* b1 = (const float*)d_in[3];
    const float* w2 = (const float*)d_in[4];
    const float* b2 = (const float*)d_in[5];
    float* out = (float*)d_out;

    char* ws = (char*)d_ws;
    size_t o = 0;
    auto alloc = [&](size_t b) { size_t r = o; o = (o + b + 255) & ~(size_t)255; return r; };
    int*    counts  = (int*)(ws + alloc(NE * 4));
    int*    bases   = (int*)(ws + alloc(NE * 4));
    float*  imp     = (float*)(ws + alloc(NE * 4));
    int*    tki     = (int*)(ws + alloc(SLOTS * 4));
    float*  tkg     = (float*)(ws + alloc(SLOTS * 4));
    int*    tok_ids = (int*)(ws + alloc(SLOTS * 4));
    int*    slotmap = (int*)(ws + alloc(SLOTS * 4));
    bf16_t* xb      = (bf16_t*)(ws + alloc((size_t)N_TOK * DIM * 2));
    size_t  w1t_off = alloc((size_t)NE * HID * DIM * 2);
    bf16_t* w1t     = (bf16_t*)(ws + w1t_off);
    bf16_t* ybuf    = (bf16_t*)(ws + w1t_off);   // [2][SLOTS][OUTD] aliases w1t (dead after GEMM-1)
    bf16_t* w2t     = (bf16_t*)(ws + alloc((size_t)NE * OUTD * HID * 2));
    bf16_t* hbuf    = (bf16_t*)(ws + alloc((size_t)SLOTS * HID * 2));
    (void)ws_size; (void)n_in; (void)in_sizes;

    hipFuncSetAttribute((const void*)&k_gemm<0>, hipFuncAttributeMaxDynamicSharedMemorySize, 98304);
    hipFuncSetAttribute((const void*)&k_gemm<1>, hipFuncAttributeMaxDynamicSharedMemorySize, 98304);

    // no atomics anywhere -> no workspace zeroing needed
    k_gating<<<N_TOK / 8, 512, 0, stream>>>(x, wg, xb, tki, tkg);
    k_count<<<NE, 256, 0, stream>>>(tki, tkg, counts, imp);
    k_finalize<<<1, 64, 0, stream>>>(imp, counts, bases, out + (size_t)N_TOK * OUTD);
    k_place<<<NE, 256, 0, stream>>>(tki, bases, tok_ids, slotmap);
    k_transpose<<<4096, 512, 0, stream>>>(w1, w2, w1t, w2t);

    // 256 blocks = 8 XCD-pinned experts x 32 worklist slots; 96 KiB dynamic LDS
    k_gemm<0><<<256, 512, 98304, stream>>>(xb, w1t, b1, tok_ids, bases, counts, hbuf);
    k_gemm<1><<<256, 512, 98304, stream>>>(hbuf, w2t, b2, tok_ids, bases, counts, ybuf);

    k_combine<<<N_TOK, 256, 0, stream>>>(ybuf, slotmap, tkg, out);
}

// Round 16
// 340.716 us; speedup vs baseline: 1.4478x; 1.0516x over previous
//
#include <hip/hip_runtime.h>
#include <hip/hip_bf16.h>
#include <stdint.h>

#define N_TOK 4096
#define DIM   1024
#define NE    8
#define HID   4096
#define OUTD  1024
#define TOPK  2
#define SLOTS (N_TOK*TOPK)
#define MAXT0 640   // 16 * max ΣNTy (= 8192/256 + 8)
#define MAXT1 320   // 8 * max ΣNTy

typedef __bf16 bf16_t;
typedef __attribute__((ext_vector_type(8))) __bf16 bf16x8;
typedef __attribute__((ext_vector_type(4))) __bf16 bf16x4;
typedef __attribute__((ext_vector_type(4))) float  f32x4;

static __device__ __forceinline__ uint32_t pk2(float a, float b) {
    __bf16 x = (__bf16)a, y = (__bf16)b;
    return (uint32_t)__builtin_bit_cast(uint16_t, x) |
          ((uint32_t)__builtin_bit_cast(uint16_t, y) << 16);
}

// ---------------- gating (fp64 logits, top-2, softmax) + x -> bf16 cast ----------------
__global__ __launch_bounds__(512)
void k_gating(const float* __restrict__ x, const float* __restrict__ wg,
              bf16_t* __restrict__ xb,
              int* __restrict__ tki, float* __restrict__ tkg) {
    int n = blockIdx.x * 8 + (threadIdx.x >> 6);
    int lane = threadIdx.x & 63;
    const float* xr = x + (size_t)n * DIM;
    double acc[NE];
#pragma unroll
    for (int e = 0; e < NE; ++e) acc[e] = 0.0;
#pragma unroll
    for (int i = 0; i < 4; ++i) {
        int d0 = i * 256 + lane * 4;
        float4 v = *(const float4*)&xr[d0];
        bf16x4 o;
        o[0] = (__bf16)v.x; o[1] = (__bf16)v.y; o[2] = (__bf16)v.z; o[3] = (__bf16)v.w;
        *(bf16x4*)&xb[(size_t)n * DIM + d0] = o;
        const float* wr = wg + (size_t)d0 * NE;
#pragma unroll
        for (int j = 0; j < 4; ++j) {
            double xv = (double)((&v.x)[j]);
#pragma unroll
            for (int e = 0; e < NE; ++e) acc[e] += xv * (double)wr[j * NE + e];
        }
    }
#pragma unroll
    for (int e = 0; e < NE; ++e)
        for (int off = 32; off > 0; off >>= 1) acc[e] += __shfl_xor(acc[e], off);
    if (lane == 0) {
        int i0 = 0; double v0 = acc[0];
#pragma unroll
        for (int e = 1; e < NE; ++e) if (acc[e] > v0) { v0 = acc[e]; i0 = e; }
        int i1 = -1; double v1 = -1e300;
#pragma unroll
        for (int e = 0; e < NE; ++e) if (e != i0 && acc[e] > v1) { v1 = acc[e]; i1 = e; }
        double e1 = exp(v1 - v0);
        double s = 1.0 + e1;
        tki[n*2]   = i0;  tki[n*2+1] = i1;
        tkg[n*2]   = (float)(1.0 / s);
        tkg[n*2+1] = (float)(e1 / s);
    }
}

// ------- merged routing: counts + importance + aux + bases + tile-prefix + placement -------
// grid = NE blocks x 256 thr. Every block deterministically computes ALL experts' counts
// (fixed-order butterfly + 4-wave sum); block 0 publishes scalars; block e places expert e
// via ballot prefix-scan. No atomics anywhere.
__global__ __launch_bounds__(256)
void k_route(const int* __restrict__ tki, const float* __restrict__ tkg,
             int* __restrict__ counts, int* __restrict__ bases,
             int* __restrict__ tb0, int* __restrict__ tb1,
             float* __restrict__ aux_out,
             int* __restrict__ tok_ids, int* __restrict__ slotmap) {
    const int e = blockIdx.x, t = threadIdx.x;
    const int wid = t >> 6, lane = t & 63;
    int   lc[NE]; float lg[NE];
#pragma unroll
    for (int k = 0; k < NE; ++k) { lc[k] = 0; lg[k] = 0.f; }
    for (int i = t; i < SLOTS; i += 256) {
        int ee = tki[i]; float gg = tkg[i];
#pragma unroll
        for (int k = 0; k < NE; ++k) if (ee == k) { lc[k]++; lg[k] += gg; }
    }
#pragma unroll
    for (int k = 0; k < NE; ++k)
        for (int off = 32; off > 0; off >>= 1) {
            lc[k] += __shfl_xor(lc[k], off);
            lg[k] += __shfl_xor(lg[k], off);
        }
    __shared__ int   wcI[4][NE];
    __shared__ float wcF[4][NE];
    if (lane == 0)
#pragma unroll
        for (int k = 0; k < NE; ++k) { wcI[wid][k] = lc[k]; wcF[wid][k] = lg[k]; }
    __syncthreads();
    int cnt[NE];
#pragma unroll
    for (int k = 0; k < NE; ++k)
        cnt[k] = wcI[0][k] + wcI[1][k] + wcI[2][k] + wcI[3][k];
    if (e == 0 && t == 0) {
        float gs[NE];
#pragma unroll
        for (int k = 0; k < NE; ++k)
            gs[k] = wcF[0][k] + wcF[1][k] + wcF[2][k] + wcF[3][k];
        float m = 0.f;
        for (int k = 0; k < NE; ++k) m += gs[k];
        m /= (float)NE;
        float var = 0.f;
        for (int k = 0; k < NE; ++k) { float d = gs[k] - m; var += d * d; }
        var /= (float)NE;
        aux_out[0] = 0.01f * var / (m * m + 1e-10f);
        int b = 0, c0 = 0, c1 = 0;
        tb0[0] = 0; tb1[0] = 0;
        for (int k = 0; k < NE; ++k) {
            counts[k] = cnt[k]; bases[k] = b; b += cnt[k];
            int nty = (cnt[k] + 255) >> 8;
            c0 += 16 * nty; c1 += 8 * nty;
            tb0[k+1] = c0; tb1[k+1] = c1;
        }
    }
    // placement for expert e
    int run = 0;
    for (int k = 0; k < e; ++k) run += cnt[k];
    __shared__ int wc[4];
    for (int base = 0; base < SLOTS; base += 256) {
        int i = base + t;
        bool f = (tki[i] == e);
        unsigned long long bl = __ballot(f);
        int pre = __popcll(bl & ((1ull << lane) - 1ull));
        if (lane == 0) wc[wid] = __popcll(bl);
        __syncthreads();
        int woff = 0;
#pragma unroll
        for (int u = 0; u < 4; ++u) if (u < wid) woff += wc[u];
        int tot = wc[0] + wc[1] + wc[2] + wc[3];
        if (f) { int s = run + woff + pre; tok_ids[s] = i >> 1; slotmap[i] = s; }
        run += tot;
        __syncthreads();
    }
}

// ---------------- W [E][R][C] fp32 -> Wt [E][C][R] bf16 (R15 v3 geometry) ----------------
__global__ __launch_bounds__(512)
void k_transpose(const float* __restrict__ w1, const float* __restrict__ w2,
                 bf16_t* __restrict__ w1t, bf16_t* __restrict__ w2t) {
    __shared__ bf16_t tT[64][264];        // 33.8 KB
    const int bx = blockIdx.x;
    const float* src; bf16_t* dst; int R, C, ry, cx;
    if (bx < 2048) {                      // w1: [8][1024][4096] -> [8][4096][1024]
        int e = bx >> 8, rem = bx & 255;
        ry = rem >> 6; cx = rem & 63;
        src = w1 + (size_t)e * DIM * HID; dst = w1t + (size_t)e * DIM * HID;
        R = DIM; C = HID;
    } else {                              // w2: [8][4096][1024] -> [8][1024][4096]
        int b2 = bx - 2048;
        int e = b2 >> 8, rem = b2 & 255;
        ry = rem >> 4; cx = rem & 15;
        src = w2 + (size_t)e * HID * OUTD; dst = w2t + (size_t)e * HID * OUTD;
        R = HID; C = OUTD;
    }
    const int r0 = ry * 256, c0 = cx * 64;
    const int tx = threadIdx.x & 15;
    const int ta = threadIdx.x >> 4;
#pragma unroll
    for (int p = 0; p < 4; ++p) {
        int r = 2 * ta + 64 * p;
        float4 va = *(const float4*)&src[(size_t)(r0 + r)     * C + c0 + tx * 4];
        float4 vb = *(const float4*)&src[(size_t)(r0 + r + 1) * C + c0 + tx * 4];
#pragma unroll
        for (int j = 0; j < 4; ++j)
            *(uint32_t*)&tT[tx * 4 + j][r] = pk2((&va.x)[j], (&vb.x)[j]);
    }
    __syncthreads();
    const int w = threadIdx.x >> 6, l = threadIdx.x & 63;
    const int ccb = w * 2 + (l >> 5);
    const int rb  = (l & 31) * 8;
#pragma unroll
    for (int q = 0; q < 4; ++q) {
        int cc = q * 16 + ccb;
        bf16x8 o = *(const bf16x8*)&tT[cc][rb];
        *(bf16x8*)&dst[(size_t)(c0 + cc) * R + r0 + rb] = o;
    }
}

// ====== grouped GEMM, 256x256 tile, BK=32, 8 waves (2M x 4N), per-wave 128x64 ======
// R16: FLAT WORKLIST — one tile per block, grid = worst-case tile count; block decodes
// (e, panel, y, kslot) from device-side tile-prefix tb[]; excess blocks exit. HW dispatch
// backfills CUs as blocks retire -> load-balanced across skewed experts (fixes R15's
// per-expert 32-block pinning: tiles/expert 48..112 left CUs idle; MfmaUtil 23%).
// Inner loop verbatim R13/R15 (counted-vmcnt 3-buffer read-ahead, 0 bank conflicts).
template <int MODE>
__global__ __launch_bounds__(512, 2)
void k_gemm(const bf16_t* __restrict__ A,    // MODE0: xb [N][DIM]; MODE1: hbuf [SLOTS][HID]
            const bf16_t* __restrict__ Bt,   // MODE0: w1t [E][HID][DIM]; MODE1: w2t [E][OUTD][HID]
            const float* __restrict__ bias,
            const int* __restrict__ tok_ids,
            const int* __restrict__ bases,
            const int* __restrict__ counts,
            const int* __restrict__ tb,      // [NE+1] tile prefix for this mode
            bf16_t* __restrict__ Y) {
    constexpr int KD   = (MODE == 0) ? DIM : HID;
    constexpr int ND   = (MODE == 0) ? HID : OUTD;
    constexpr int KLEN = (MODE == 0) ? DIM : (HID / 2);   // 1024 / 2048
    constexpr int KT   = KLEN / 32;                       // 32 / 64
    constexpr int BUFE = 16384;               // A 8192 + B 8192 elems (32 KiB)

    const int ti = blockIdx.x;
    if (ti >= tb[NE]) return;
    int e = 0;
#pragma unroll
    for (int k = 1; k < NE; ++k) if (ti >= tb[k]) e = k;
    const int local = ti - tb[e];
    const int ne = counts[e];
    const int b0 = bases[e];
    int panel, y, kslot = 0;
    if (MODE == 0) { y = local >> 4; panel = local & 15; }          // panel fastest
    else           { y = local >> 3; int q = local & 7; panel = q >> 1; kslot = q & 1; }
    const int m0 = y * 256, n0 = panel * 256;
    const int koff = (MODE == 0) ? 0 : kslot * KLEN;
    bf16_t* __restrict__ Yw = (MODE == 0) ? Y : (Y + (size_t)kslot * SLOTS * OUTD);

    extern __shared__ bf16_t lds[];           // 3 * BUFE elems = 96 KiB

    const int t = threadIdx.x, w = t >> 6, L = t & 63;
    const int wm = w >> 2, wn = w & 3;        // 2M x 4N; per-wave out 128x64
    const int lr = L & 15, lq = L >> 4;
    const int srow  = L >> 2;
    const int sslot = L & 3;

    int offA[8], offB[4];
#pragma unroll
    for (int i = 0; i < 8; ++i) {
        int r = wm * 128 + i * 16 + lr;
        offA[i] = r * 32 + ((lq ^ ((r >> 1) & 3)) << 3);
    }
#pragma unroll
    for (int j = 0; j < 4; ++j) {
        int r = wn * 64 + j * 16 + lr;
        offB[j] = 8192 + r * 32 + ((lq ^ ((r >> 1) & 3)) << 3);
    }
    int sdstA[2], sdstB[2];
#pragma unroll
    for (int g = 0; g < 2; ++g) {
        sdstA[g] = (g * 128 + w * 16) * 32;
        sdstB[g] = 8192 + (g * 128 + w * 16) * 32;
    }

#define GLL(srcp, dste) __builtin_amdgcn_global_load_lds( \
        (const __attribute__((address_space(1))) uint32_t*)(srcp), \
        (__attribute__((address_space(3))) uint32_t*)(lds + (dste)), 16, 0, 0)
#define STAGE(Tt, bsl) { \
        _Pragma("unroll") for (int g_ = 0; g_ < 2; ++g_) { \
            GLL(aptr[g_] + (Tt) * 32, (bsl) * BUFE + sdstA[g_]); \
            GLL(bptr[g_] + (Tt) * 32, (bsl) * BUFE + sdstB[g_]); } }

    const bf16_t* aptr[2];
    const bf16_t* bptr[2];
#pragma unroll
    for (int g = 0; g < 2; ++g) {
        int row = g * 128 + w * 16 + srow;
        int gk  = sslot ^ ((row >> 1) & 3);
        int mm = m0 + row;
        int rr = (mm < ne) ? mm : (ne - 1);
        size_t arow = (MODE == 0) ? (size_t)tok_ids[b0 + rr] * KD : (size_t)(b0 + rr) * KD;
        aptr[g] = A + arow + koff + gk * 8;
        bptr[g] = Bt + ((size_t)e * ND + n0 + row) * KD + koff + gk * 8;
    }

    f32x4 acc[8][4];
#pragma unroll
    for (int i = 0; i < 8; ++i)
#pragma unroll
        for (int j = 0; j < 4; ++j) acc[i][j] = (f32x4){0.f, 0.f, 0.f, 0.f};

    STAGE(0, 0); STAGE(1, 1);

    int cb = 0;
    int nb = 2;
    for (int T = 0; T < KT; ++T) {
        if (T < KT - 1) { asm volatile("s_waitcnt vmcnt(4)" ::: "memory"); }
        else            { asm volatile("s_waitcnt vmcnt(0)" ::: "memory"); }
        __builtin_amdgcn_s_barrier();
        if (T + 2 < KT) STAGE(T + 2, nb);

        bf16x8 fb[4], fa[8];
#pragma unroll
        for (int j = 0; j < 4; ++j) fb[j] = *(const bf16x8*)(lds + cb * BUFE + offB[j]);
#pragma unroll
        for (int i = 0; i < 4; ++i) fa[i] = *(const bf16x8*)(lds + cb * BUFE + offA[i]);
        __builtin_amdgcn_sched_barrier(0);
#pragma unroll
        for (int i = 4; i < 8; ++i) fa[i] = *(const bf16x8*)(lds + cb * BUFE + offA[i]);
        __builtin_amdgcn_sched_barrier(0);
        asm volatile("s_waitcnt lgkmcnt(4)" ::: "memory");   // fb + fa0-3 done
        __builtin_amdgcn_sched_barrier(0);
        __builtin_amdgcn_s_setprio(1);
#pragma unroll
        for (int i = 0; i < 4; ++i)
#pragma unroll
            for (int j = 0; j < 4; ++j)
                acc[i][j] = __builtin_amdgcn_mfma_f32_16x16x32_bf16(fb[j], fa[i], acc[i][j], 0, 0, 0);
        __builtin_amdgcn_s_setprio(0);
        asm volatile("s_waitcnt lgkmcnt(0)" ::: "memory");   // fa4-7 done (hidden under mh0)
        __builtin_amdgcn_sched_barrier(0);
        __builtin_amdgcn_s_setprio(1);
#pragma unroll
        for (int i = 4; i < 8; ++i)
#pragma unroll
            for (int j = 0; j < 4; ++j)
                acc[i][j] = __builtin_amdgcn_mfma_f32_16x16x32_bf16(fb[j], fa[i], acc[i][j], 0, 0, 0);
        __builtin_amdgcn_s_setprio(0);

        cb = (cb == 2) ? 0 : cb + 1;
        nb = (nb == 2) ? 0 : nb + 1;
    }

    // ---------------- epilogue: bf16 store ----------------
    const int kbias = (MODE == 0) ? 1 : (kslot == 0 ? 1 : 0);
#pragma unroll
    for (int i = 0; i < 8; ++i) {
        int gm = m0 + wm * 128 + i * 16 + lr;
        if (gm < ne) {
#pragma unroll
            for (int j = 0; j < 4; ++j) {
                int gn = n0 + wn * 64 + j * 16 + lq * 4;
                f32x4 bv = *(const f32x4*)&bias[(size_t)e * ND + gn];
                bf16x4 hv;
#pragma unroll
                for (int r = 0; r < 4; ++r) {
                    float v = acc[i][j][r];
                    if (kbias) v += bv[r];
                    if (MODE == 0) v = fmaxf(v, 0.f);
                    hv[r] = (__bf16)v;
                }
                *(bf16x4*)&Yw[(size_t)(b0 + gm) * ND + gn] = hv;
            }
        }
    }
#undef STAGE
#undef GLL
}

// ---------------- combine: out[n] = g0*(y0a+y0b) + g1*(y1a+y1b) (fp32) ----------------
__global__ void k_combine(const bf16_t* __restrict__ ybuf,   // [2][SLOTS][OUTD]
                          const int* __restrict__ slotmap,
                          const float* __restrict__ tkg,
                          float* __restrict__ out) {
    int n = blockIdx.x;
    int d = threadIdx.x * 4;
    int s0 = slotmap[2 * n], s1 = slotmap[2 * n + 1];
    float g0 = tkg[2 * n],  g1 = tkg[2 * n + 1];
    const bf16_t* y2 = ybuf + (size_t)SLOTS * OUTD;
    bf16x4 a0 = *(const bf16x4*)&ybuf[(size_t)s0 * OUTD + d];
    bf16x4 a1 = *(const bf16x4*)&y2  [(size_t)s0 * OUTD + d];
    bf16x4 c0 = *(const bf16x4*)&ybuf[(size_t)s1 * OUTD + d];
    bf16x4 c1 = *(const bf16x4*)&y2  [(size_t)s1 * OUTD + d];
    f32x4 o;
#pragma unroll
    for (int r = 0; r < 4; ++r)
        o[r] = g0 * ((float)a0[r] + (float)a1[r]) + g1 * ((float)c0[r] + (float)c1[r]);
    *(f32x4*)&out[(size_t)n * OUTD + d] = o;
}

extern "C" void kernel_launch(void* const* d_in, const int* in_sizes, int n_in,
                              void* d_out, int out_size, void* d_ws, size_t ws_size,
                              hipStream_t stream) {
    const float* x  = (const float*)d_in[0];
    const float* wg = (const float*)d_in[1];
    const float* w1 = (const float*)d_in[2];
    const float* b1 = (const float*)d_in[3];
    const float* w2 = (const float*)d_in[4];
    const float* b2 = (const float*)d_in[5];
    float* out = (float*)d_out;

    char* ws = (char*)d_ws;
    size_t o = 0;
    auto alloc = [&](size_t b) { size_t r = o; o = (o + b + 255) & ~(size_t)255; return r; };
    int*    counts  = (int*)(ws + alloc(NE * 4));
    int*    bases   = (int*)(ws + alloc(NE * 4));
    int*    tb0     = (int*)(ws + alloc((NE + 1) * 4));
    int*    tb1     = (int*)(ws + alloc((NE + 1) * 4));
    int*    tki     = (int*)(ws + alloc(SLOTS * 4));
    float*  tkg     = (float*)(ws + alloc(SLOTS * 4));
    int*    tok_ids = (int*)(ws + alloc(SLOTS * 4));
    int*    slotmap = (int*)(ws + alloc(SLOTS * 4));
    bf16_t* xb      = (bf16_t*)(ws + alloc((size_t)N_TOK * DIM * 2));
    size_t  w1t_off = alloc((size_t)NE * HID * DIM * 2);
    bf16_t* w1t     = (bf16_t*)(ws + w1t_off);
    bf16_t* ybuf    = (bf16_t*)(ws + w1t_off);   // [2][SLOTS][OUTD] aliases w1t (dead after GEMM-1)
    bf16_t* w2t     = (bf16_t*)(ws + alloc((size_t)NE * OUTD * HID * 2));
    bf16_t* hbuf    = (bf16_t*)(ws + alloc((size_t)SLOTS * HID * 2));
    (void)ws_size; (void)n_in; (void)in_sizes;

    hipFuncSetAttribute((const void*)&k_gemm<0>, hipFuncAttributeMaxDynamicSharedMemorySize, 98304);
    hipFuncSetAttribute((const void*)&k_gemm<1>, hipFuncAttributeMaxDynamicSharedMemorySize, 98304);

    k_gating<<<N_TOK / 8, 512, 0, stream>>>(x, wg, xb, tki, tkg);
    k_route<<<NE, 256, 0, stream>>>(tki, tkg, counts, bases, tb0, tb1,
                                    out + (size_t)N_TOK * OUTD, tok_ids, slotmap);
    k_transpose<<<4096, 512, 0, stream>>>(w1, w2, w1t, w2t);

    // flat worklist: one tile per block; excess blocks exit on tb[NE]
    k_gemm<0><<<MAXT0, 512, 98304, stream>>>(xb, w1t, b1, tok_ids, bases, counts, tb0, hbuf);
    k_gemm<1><<<MAXT1, 512, 98304, stream>>>(hbuf, w2t, b2, tok_ids, bases, counts, tb1, ybuf);

    k_combine<<<N_TOK, 256, 0, stream>>>(ybuf, slotmap, tkg, out);
}